// Round 5
// baseline (131.235 us; speedup 1.0000x reference)
//
#include <hip/hip_runtime.h>

// out[b, p] = sum_s prob[b,s] * param[p, idx[b,s]]
//   param: (512*2048, 64) fp32 = 256 MiB ; out: (64, 512*2048) fp32 = 256 MiB
// Streaming floor ~= 537 MB / 6.29 TB/s (measured R+W copy ceiling) ~= 85 us.
//
// Round 5: round-3 geometry (TILE=256, 512 thr, 64 KiB LDS, same verified
// conflict-free swizzle + 1 KiB/wave stores) + persistent blocks with a
// software pipeline:
//   prologue: load+stage tile 0
//   per tile: barrier -> issue loads(t+1)->regs -> gather(t) [loads fly under
//             LDS reads + stores] -> barrier -> ds_write regs
// so every block keeps reads AND writes in flight continuously (round 4's
// lesson: never shrink per-batch store chunks below ~1 KiB; round 3's lesson:
// phase-serialized blocks leave ~11% BW on the table).

#define NPOS   (512 * 2048)
#define NBANK  64
#define NBATCH 64
#define TILE   256
#define BLK    512
#define NBLK   512                       // 2 blocks/CU -> fully resident
#define TPB    (NPOS / TILE / NBLK)      // 8 tiles per block

typedef float f32x4 __attribute__((ext_vector_type(4)));
typedef int   i32x4 __attribute__((ext_vector_type(4)));

__global__ __launch_bounds__(BLK, 2) void vparam_kernel(
    const float* __restrict__ param,
    const int*   __restrict__ sel,
    const float* __restrict__ prob,
    float*       __restrict__ out)
{
    __shared__ float lds[NBANK * TILE];   // 64 KiB -> 2 blocks/CU

    const int tid  = threadIdx.x;
    const int wave = tid >> 6;            // 0..7
    const int lane = tid & 63;
    const int pw   = lane * 4;            // gather: lane's 4 positions (words)
    const int sp   = tid >> 4;            // staging: p low bits (0..31)
    const int k0   = (tid & 15) * 4;      // staging: first of 4 banks

    const i32x4* sel4  = (const i32x4*)sel;   // uniform b -> s_load
    const f32x4* prob4 = (const f32x4*)prob;

    f32x4 r[8];                           // next-tile staging registers
    int tile = blockIdx.x * TPB;

    // ---- prologue: load + stage tile 0 ----
    {
        const f32x4* g4 = (const f32x4*)(param + (size_t)tile * (TILE * NBANK));
        #pragma unroll
        for (int i = 0; i < 8; ++i)
            r[i] = __builtin_nontemporal_load(&g4[i * BLK + tid]);
        #pragma unroll
        for (int i = 0; i < 8; ++i) {
            int p = i * 32 + sp;
            #pragma unroll
            for (int j = 0; j < 4; ++j) {
                int k = k0 + j;
                lds[k * TILE + (p ^ (k & 28))] = r[i][j];  // 2 lanes/bank -> free
            }
        }
    }

    #pragma unroll 1
    for (int t = 0; t < TPB; ++t) {
        __syncthreads();                  // staged tile visible to all waves

        if (t + 1 < TPB) {                // issue next tile's loads early
            const f32x4* g4 = (const f32x4*)(param + (size_t)(tile + 1) * (TILE * NBANK));
            #pragma unroll
            for (int i = 0; i < 8; ++i)
                r[i] = __builtin_nontemporal_load(&g4[i * BLK + tid]);
        }

        // ---- gather current tile: b128 LDS reads, 1 KiB/wave nt stores ----
        const size_t obase = (size_t)tile * TILE;
        #pragma unroll
        for (int j = 0; j < 8; ++j) {
            int b = __builtin_amdgcn_readfirstlane(wave * 8 + j);
            i32x4 iv = sel4[b];
            f32x4 wv = prob4[b];
            f32x4 a0 = *(const f32x4*)&lds[iv.x * TILE + (pw ^ (iv.x & 28))];
            f32x4 a1 = *(const f32x4*)&lds[iv.y * TILE + (pw ^ (iv.y & 28))];
            f32x4 a2 = *(const f32x4*)&lds[iv.z * TILE + (pw ^ (iv.z & 28))];
            f32x4 a3 = *(const f32x4*)&lds[iv.w * TILE + (pw ^ (iv.w & 28))];
            f32x4 acc = a0 * wv.x + a1 * wv.y + a2 * wv.z + a3 * wv.w;
            __builtin_nontemporal_store(acc,
                (f32x4*)(out + (size_t)b * NPOS + obase) + lane);
        }

        if (t + 1 < TPB) {
            __syncthreads();              // all reads of current tile done
            #pragma unroll
            for (int i = 0; i < 8; ++i) { // stage next tile (waits its loads only)
                int p = i * 32 + sp;
                #pragma unroll
                for (int j = 0; j < 4; ++j) {
                    int k = k0 + j;
                    lds[k * TILE + (p ^ (k & 28))] = r[i][j];
                }
            }
        }
        ++tile;
    }
}

extern "C" void kernel_launch(void* const* d_in, const int* in_sizes, int n_in,
                              void* d_out, int out_size, void* d_ws, size_t ws_size,
                              hipStream_t stream) {
    const float* param = (const float*)d_in[0];
    const int*   sel   = (const int*)d_in[1];
    const float* prob  = (const float*)d_in[2];
    float*       out   = (float*)d_out;

    vparam_kernel<<<dim3(NBLK), dim3(BLK), 0, stream>>>(param, sel, prob, out);
}

// Round 6
// 130.305 us; speedup vs baseline: 1.0071x; 1.0071x over previous
//
#include <hip/hip_runtime.h>

// out[b, p] = sum_s prob[b,s] * param[p, idx[b,s]]
//   param: (512*2048, 64) fp32 = 256 MiB ; out: (64, 512*2048) fp32 = 256 MiB
// Floor ~= 537 MB / 6.29 TB/s (measured mixed R+W copy ceiling) ~= 85 us.
//
// Round 6: persistent blocks + double-buffered LDS, ONE barrier per tile,
// placed right after the ds_writes (LDS ops) — a full phase away from the
// output stores (round-5 lesson: a barrier right after nt stores drains
// vmcnt(0) on just-issued HBM writes) and from load consumption (counted
// vmcnt wait before ds_write, not a drain). Store chunks stay 1 KiB/wave
// (round-4 lesson). Per-tile patterns byte-identical to round 3 (verified
// conflict-free swizzle, b128 gather, coalesced 1 KiB stores).
//
//   load r <- tile0
//   for t: ds_write buf[t&1] <- r ; barrier ; load r <- t+1 ;
//          gather buf[t&1] -> 1KiB/wave nt stores
//
// Safety of the single barrier: it orders ds_write(t) before gather(t);
// ds_write(t+1) targets the other buffer; no wave can lag a full iteration
// (it must clear barrier(t) first), so gather(t-1) is finished chip-wide
// before any ds_write(t+1)... and buf[(t+1)&1] readers finished at barrier(t).

#define NPOS   (512 * 2048)
#define NBANK  64
#define NBATCH 64
#define TILE   256
#define BLK    512
#define NBLK   256                        // exactly 1 block per CU
#define TPB    (NPOS / TILE / NBLK)       // 16 tiles per block

typedef float f32x4 __attribute__((ext_vector_type(4)));
typedef int   i32x4 __attribute__((ext_vector_type(4)));

__global__ __launch_bounds__(BLK, 2) void vparam_kernel(
    const float* __restrict__ param,
    const int*   __restrict__ sel,
    const float* __restrict__ prob,
    float*       __restrict__ out)
{
    __shared__ float lds[2][NBANK * TILE];   // 128 KiB -> 1 block/CU

    const int tid  = threadIdx.x;
    const int wave = tid >> 6;            // 0..7
    const int lane = tid & 63;
    const int pw   = lane * 4;            // gather: lane's 4 positions (words)
    const int sp   = tid >> 4;            // staging: p low bits (0..31)
    const int k0   = (tid & 15) * 4;      // staging: first of 4 banks

    const i32x4* sel4  = (const i32x4*)sel;   // uniform b -> s_load
    const f32x4* prob4 = (const f32x4*)prob;

    f32x4 r[8];
    const int t0 = blockIdx.x * TPB;

    // prologue: loads for tile 0
    {
        const f32x4* g4 = (const f32x4*)(param + (size_t)t0 * (TILE * NBANK));
        #pragma unroll
        for (int i = 0; i < 8; ++i)
            r[i] = __builtin_nontemporal_load(&g4[i * BLK + tid]);
    }

    #pragma unroll 1
    for (int t = 0; t < TPB; ++t) {
        float* __restrict__ L = lds[t & 1];

        // stage tile t: regs -> LDS (2 lanes/bank -> free); counted vmcnt wait
        #pragma unroll
        for (int i = 0; i < 8; ++i) {
            int p = i * 32 + sp;
            #pragma unroll
            for (int j = 0; j < 4; ++j) {
                int k = k0 + j;
                L[k * TILE + (p ^ (k & 28))] = r[i][j];
            }
        }

        __syncthreads();   // the only barrier; stores from t-1 are long done

        if (t + 1 < TPB) { // prefetch tile t+1 under the gather
            const f32x4* g4 = (const f32x4*)(param + (size_t)(t0 + t + 1) * (TILE * NBANK));
            #pragma unroll
            for (int i = 0; i < 8; ++i)
                r[i] = __builtin_nontemporal_load(&g4[i * BLK + tid]);
        }

        // gather tile t: b128 LDS reads, 1 KiB/wave coalesced nt stores
        const size_t obase = (size_t)(t0 + t) * TILE;
        #pragma unroll
        for (int j = 0; j < 8; ++j) {
            int b = __builtin_amdgcn_readfirstlane(wave * 8 + j);
            i32x4 iv = sel4[b];
            f32x4 wv = prob4[b];
            f32x4 a0 = *(const f32x4*)&L[iv.x * TILE + (pw ^ (iv.x & 28))];
            f32x4 a1 = *(const f32x4*)&L[iv.y * TILE + (pw ^ (iv.y & 28))];
            f32x4 a2 = *(const f32x4*)&L[iv.z * TILE + (pw ^ (iv.z & 28))];
            f32x4 a3 = *(const f32x4*)&L[iv.w * TILE + (pw ^ (iv.w & 28))];
            f32x4 acc = a0 * wv.x + a1 * wv.y + a2 * wv.z + a3 * wv.w;
            __builtin_nontemporal_store(acc,
                (f32x4*)(out + (size_t)b * NPOS + obase) + lane);
        }
    }
}

extern "C" void kernel_launch(void* const* d_in, const int* in_sizes, int n_in,
                              void* d_out, int out_size, void* d_ws, size_t ws_size,
                              hipStream_t stream) {
    const float* param = (const float*)d_in[0];
    const int*   sel   = (const int*)d_in[1];
    const float* prob  = (const float*)d_in[2];
    float*       out   = (float*)d_out;

    vparam_kernel<<<dim3(NBLK), dim3(BLK), 0, stream>>>(param, sel, prob, out);
}

// Round 8
// 100.474 us; speedup vs baseline: 1.3062x; 1.2969x over previous
//
#include <hip/hip_runtime.h>

// out[b, p] = sum_s prob[b,s] * param[p, idx[b,s]]
//   param: (512*2048, 64) fp32 = 256 MiB ; out: (64, 512*2048) fp32 = 256 MiB
// Floor ~= 537 MB / 6.29 TB/s (measured mixed R+W copy ceiling) ~= 85 us.
//
// Round 8: R3 skeleton (one tile per block, single __syncthreads whose vmcnt
// drain covers only the block's own needed staging loads), but TILE=128 /
// 32 KiB LDS -> 4 blocks/CU = 32 waves/CU (full occupancy). Mechanism: the
// 6.29 TB/s copy reference is fully R/W-mixed with max occupancy and no
// barriers — occupancy/issue diversity is what saturates HBM (R2->R3 showed
// +waves = +BW; persistent low-occupancy variants R5-R7 all regressed).
//
// LDS layout: bank-major + XOR swizzle, word(k,p) = k*128 + (p ^ f(k)),
// f(k) = ((k>>2)&7)<<2.
//   staging writes: bank = (p ^ f) mod 32 -> exactly 2 lanes/bank (free)
//   gather: ds_read_b64, wave reads a permuted contiguous 512 B bank-row
//           -> uniform 4 words/bank = b64 natural minimum (conflict-free)
//   stores: dwordx2, 512 B/wave contiguous per batch (8 streams/wave)

#define NPOS   (512 * 2048)
#define NBANK  64
#define NBATCH 64
#define TILE   128
#define BLK    512
#define NBLK   (NPOS / TILE)   // 8192 blocks

typedef float f32x4 __attribute__((ext_vector_type(4)));
typedef float f32x2 __attribute__((ext_vector_type(2)));
typedef int   i32x4 __attribute__((ext_vector_type(4)));

__global__ __launch_bounds__(BLK, 8) void vparam_kernel(
    const float* __restrict__ param,
    const int*   __restrict__ sel,
    const float* __restrict__ prob,
    float*       __restrict__ out)
{
    __shared__ float lds[NBANK * TILE];   // 32 KiB -> 4 blocks/CU (wave-capped)

    const int tid       = threadIdx.x;
    const int wave      = tid >> 6;       // 0..7
    const int lane      = tid & 63;
    const int tile_base = blockIdx.x * TILE;

    // ---- Stage: global (position-major) -> LDS (bank-major, swizzled) ----
    const f32x4* g4 = (const f32x4*)(param + (size_t)tile_base * NBANK);
    const int k0 = (tid & 15) * 4;        // first of 4 consecutive banks
    const int f  = (tid & 7) << 2;        // = f(k0..k0+3), identical for all 4
    #pragma unroll
    for (int i = 0; i < 4; ++i) {
        f32x4 v = __builtin_nontemporal_load(&g4[i * BLK + tid]); // 1 KiB/wave
        int p = i * 32 + (tid >> 4);      // position within tile
        #pragma unroll
        for (int j = 0; j < 4; ++j)
            lds[(k0 + j) * TILE + (p ^ f)] = v[j];   // 2 lanes/bank -> free
    }
    __syncthreads();   // vmcnt drain = own staging loads only (all needed)

    // ---- Gather: b64 LDS reads, 512 B/wave coalesced nt stores ----
    const i32x4* sel4  = (const i32x4*)sel;    // uniform b -> s_load
    const f32x4* prob4 = (const f32x4*)prob;
    const int pw = lane * 2;              // lane's 2 positions (words)

    #pragma unroll
    for (int j = 0; j < 8; ++j) {
        int b = __builtin_amdgcn_readfirstlane(wave * 8 + j);
        i32x4 iv = sel4[b];
        f32x4 wv = prob4[b];
        f32x2 a0 = *(const f32x2*)&lds[iv.x * TILE + (pw ^ (((iv.x >> 2) & 7) << 2))];
        f32x2 a1 = *(const f32x2*)&lds[iv.y * TILE + (pw ^ (((iv.y >> 2) & 7) << 2))];
        f32x2 a2 = *(const f32x2*)&lds[iv.z * TILE + (pw ^ (((iv.z >> 2) & 7) << 2))];
        f32x2 a3 = *(const f32x2*)&lds[iv.w * TILE + (pw ^ (((iv.w >> 2) & 7) << 2))];
        f32x2 acc = a0 * wv.x + a1 * wv.y + a2 * wv.z + a3 * wv.w;
        __builtin_nontemporal_store(acc,
            (f32x2*)(out + (size_t)b * NPOS + tile_base) + lane);
    }
}

extern "C" void kernel_launch(void* const* d_in, const int* in_sizes, int n_in,
                              void* d_out, int out_size, void* d_ws, size_t ws_size,
                              hipStream_t stream) {
    const float* param = (const float*)d_in[0];
    const int*   sel   = (const int*)d_in[1];
    const float* prob  = (const float*)d_in[2];
    float*       out   = (float*)d_out;

    vparam_kernel<<<dim3(NBLK), dim3(BLK), 0, stream>>>(param, sel, prob, out);
}